// Round 6
// baseline (740.859 us; speedup 1.0000x reference)
//
#include <hip/hip_runtime.h>

typedef _Float16 f16x8 __attribute__((ext_vector_type(8)));
typedef _Float16 f16x4 __attribute__((ext_vector_type(4)));
typedef _Float16 f16x2 __attribute__((ext_vector_type(2)));
typedef float f32x4 __attribute__((ext_vector_type(4)));

#define NSEQ 2048
#define DMODEL 2048
#define NHEADS 32
#define NKV 8
#define DK 64
#define MFMA16(a, b, c) __builtin_amdgcn_mfma_f32_16x16x32_f16(a, b, c, 0, 0, 0)

// ---------------- elementwise f32 -> f16 ----------------
__global__ void cvt_f32_f16(const float* __restrict__ in, _Float16* __restrict__ out, int n4) {
    int i = blockIdx.x * blockDim.x + threadIdx.x;
    int stride = gridDim.x * blockDim.x;
    for (; i < n4; i += stride) {
        float4 v = ((const float4*)in)[i];
        f16x4 h;
        h[0] = (_Float16)v.x; h[1] = (_Float16)v.y;
        h[2] = (_Float16)v.z; h[3] = (_Float16)v.w;
        ((f16x4*)out)[i] = h;
    }
}

// ---------------- transpose + convert: in f32 [R][C] -> out f16 [C][R] ----------------
__global__ __launch_bounds__(256) void transpose_cvt(const float* __restrict__ in,
                                                     _Float16* __restrict__ out,
                                                     int R, int C) {
    __shared__ float tile[32][33];
    int c0 = blockIdx.x * 32, r0 = blockIdx.y * 32;
    int tx = threadIdx.x, ty = threadIdx.y; // (32,8)
#pragma unroll
    for (int i = 0; i < 4; i++) {
        int r = r0 + ty + i * 8;
        tile[ty + i * 8][tx] = in[(long long)r * C + c0 + tx];
    }
    __syncthreads();
#pragma unroll
    for (int i = 0; i < 4; i++) {
        int c = c0 + ty + i * 8;
        out[(long long)c * R + r0 + tx] = (_Float16)tile[tx][ty + i * 8];
    }
}

// ---------------- transpose f16 [R][C] -> f16 [C][R] ----------------
__global__ __launch_bounds__(256) void transpose16(const _Float16* __restrict__ in,
                                                   _Float16* __restrict__ out,
                                                   int R, int C) {
    __shared__ _Float16 tile[32][34];
    int c0 = blockIdx.x * 32, r0 = blockIdx.y * 32;
    int tx = threadIdx.x, ty = threadIdx.y; // (32,8)
#pragma unroll
    for (int i = 0; i < 4; i++) {
        int r = r0 + ty + i * 8;
        tile[ty + i * 8][tx] = in[(long long)r * C + c0 + tx];
    }
    __syncthreads();
#pragma unroll
    for (int i = 0; i < 4; i++) {
        int c = c0 + ty + i * 8;
        out[(long long)c * R + r0 + tx] = tile[tx][ty + i * 8];
    }
}

// ---------------- RoPE cos/sin table ----------------
__global__ void rope_table(float2* __restrict__ cs) {
    int idx = blockIdx.x * blockDim.x + threadIdx.x; // 65536 total
    int n = idx >> 5, j = idx & 31;
    float e = (2.0f * j) / 64.0f;
    float invf = 1.0f / powf(10000.0f, e);
    float ang = (float)n * invf;
    float2 v; v.x = cosf(ang); v.y = sinf(ang);
    cs[idx] = v;
}

// ---------------- RoPE apply f16->f16 for K (ncols=512) ----------------
__global__ void rope_apply16(const _Float16* __restrict__ in, const float2* __restrict__ cs,
                             _Float16* __restrict__ out) {
    int idx = blockIdx.x * blockDim.x + threadIdx.x; // 2048*256
    int n = idx >> 8, rem = idx & 255;
    int hk = rem >> 5, j = rem & 31;
    float2 c = cs[n * 32 + j];
    long long base = (long long)n * 512 + hk * 64;
    float x1 = (float)in[base + j], x2 = (float)in[base + j + 32];
    out[base + j]      = (_Float16)(x1 * c.x - x2 * c.y);
    out[base + j + 32] = (_Float16)(x2 * c.x + x1 * c.y);
}

// ---------------- GEMM: C[M,N] = A[M,K] @ Bt[N,K]^T  (fp16 MFMA, f32 accum) ----------------
template <int BM, int BN, int MF, int NF, typename OutT>
__global__ __launch_bounds__(256) void gemm_bt(const _Float16* __restrict__ Ap,
                                               const _Float16* __restrict__ Bt,
                                               OutT* __restrict__ C,
                                               int K, int lda, int ldb, int ldc) {
    constexpr int LDP = 56;
    __shared__ __align__(16) _Float16 As[BM][LDP];
    __shared__ __align__(16) _Float16 Bs[BN][LDP];

    const int tid = threadIdx.x;
    const int lane = tid & 63, wid = tid >> 6;
    constexpr int WC = BN / (NF * 16);
    const int wr = wid / WC, wc = wid % WC;
    const int wm = wr * MF * 16, wn = wc * NF * 16;
    const int am = lane & 15;
    const int k0 = (lane >> 4) * 8;

    f32x4 acc[MF][NF] = {};

    const long long a_row0 = (long long)blockIdx.y * BM * lda;
    const long long b_row0 = (long long)blockIdx.x * BN * ldb;

    for (int kt = 0; kt < K; kt += 32) {
        const _Float16* A = Ap + a_row0 + kt;
        for (int c = tid; c < BM * 4; c += 256) {
            int r = c >> 2, s = c & 3;
            *(f16x8*)&As[r][s * 8] = *(const f16x8*)(A + (long long)r * lda + s * 8);
        }
        const _Float16* B = Bt + b_row0 + kt;
        for (int c = tid; c < BN * 4; c += 256) {
            int r = c >> 2, s = c & 3;
            *(f16x8*)&Bs[r][s * 8] = *(const f16x8*)(B + (long long)r * ldb + s * 8);
        }
        __syncthreads();

        f16x8 af[MF], bf[NF];
#pragma unroll
        for (int m = 0; m < MF; m++) af[m] = *(const f16x8*)&As[wm + m * 16 + am][k0];
#pragma unroll
        for (int n = 0; n < NF; n++) bf[n] = *(const f16x8*)&Bs[wn + n * 16 + am][k0];
#pragma unroll
        for (int m = 0; m < MF; m++)
#pragma unroll
            for (int n = 0; n < NF; n++)
                acc[m][n] = MFMA16(af[m], bf[n], acc[m][n]);
        __syncthreads();
    }

    const int rb = blockIdx.y * BM + wm + (lane >> 4) * 4;
    const int cb = blockIdx.x * BN + wn + am;
#pragma unroll
    for (int m = 0; m < MF; m++)
#pragma unroll
        for (int n = 0; n < NF; n++)
#pragma unroll
            for (int j = 0; j < 4; j++)
                C[(long long)(rb + m * 16 + j) * ldc + cb + n * 16] = (OutT)acc[m][n][j];
}

// ---------------- fused attention v4: per-wave two-pass, streamed stores, no barriers ------
// 256-thr blocks, 4 waves; wave w owns Q-rows [qb + w*16, +16), full 2048 kcols.
// Swapped QK^T (mfma(K,Q)): lane (g=lane>>4, c=lane&15) holds, per tile, S[qrow=c][kcol=t*16+4g+j].
// Pass 1: QK + exp -> lane-local row sums (2 shfl_xor at end). No stores.
// Pass 2: recompute QK tile, store attn = e*inv immediately (f32x4), bounce e(fp16) through
// wave-private swizzled 2KB LDS strip into A-frag layout, PV MFMAs from Vt (B-frag).
// exp clamp 11.0 in BOTH passes keeps sums/stores consistent and e fp16-safe (e<6e4).
__global__ __launch_bounds__(256) void fused_attn(
    const _Float16* __restrict__ Qraw, // [2048][2048] pre-rope fp16
    const float2*  __restrict__ cs,    // [2048][32]
    const _Float16* __restrict__ Kh,   // [2048][512] roped
    const _Float16* __restrict__ Vt,   // [512][2048]
    float* __restrict__ attn,          // [32][2048][2048]
    _Float16* __restrict__ AVh)        // [2048][2048]
{
    __shared__ __align__(16) _Float16 bounce[4][1024]; // 2 KB per wave

    const int h = blockIdx.y, qb = blockIdx.x * 64;
    const int kvh = h >> 2;
    const int tid = threadIdx.x, lane = tid & 63, w = tid >> 6;
    const int g = lane >> 4, c = lane & 15;
    const int qr = qb + w * 16 + c; // this lane's Q-row (B-frag col / S row)

    // ---- Q fragment (B-operand) + in-register RoPE ----
    const _Float16* qp = Qraw + (long long)qr * DMODEL + h * 64;
    f16x8 q0v = *(const f16x8*)(qp + g * 8);
    f16x8 q1v = *(const f16x8*)(qp + 32 + g * 8);
    const float2* csp = cs + qr * 32 + g * 8;
    f16x8 qa, qb_;
#pragma unroll
    for (int e = 0; e < 8; e++) {
        float2 cv = csp[e];
        float x1 = (float)q0v[e], x2 = (float)q1v[e];
        qa[e]  = (_Float16)(x1 * cv.x - x2 * cv.y);
        qb_[e] = (_Float16)(x2 * cv.x + x1 * cv.y);
    }

    const _Float16* Kbase = Kh + kvh * 64;
    const _Float16* Vbase = Vt + (long long)(kvh * 64) * NSEQ;
    char* mypb = (char*)&bounce[w][0];
    const int swz = (c & 7) << 4;

    // ---- pass 1: row sums (lane-local, no LDS) ----
    float l = 0.f;
#pragma unroll 2
    for (int t = 0; t < 128; t++) {
        const _Float16* kp = Kbase + (long long)(t * 16 + c) * 512;
        f16x8 kb0 = *(const f16x8*)(kp + g * 8);
        f16x8 kb1 = *(const f16x8*)(kp + 32 + g * 8);
        f32x4 acc = {0.f, 0.f, 0.f, 0.f};
        acc = MFMA16(kb0, qa, acc);
        acc = MFMA16(kb1, qb_, acc);
        l += __expf(fminf(acc[0] * 0.125f, 11.f)) + __expf(fminf(acc[1] * 0.125f, 11.f)) +
             __expf(fminf(acc[2] * 0.125f, 11.f)) + __expf(fminf(acc[3] * 0.125f, 11.f));
    }
    l += __shfl_xor(l, 16, 64);
    l += __shfl_xor(l, 32, 64);
    const float inv = 1.0f / l; // row-(c) inverse sum, uniform over g

    // ---- pass 2: recompute, stream attn stores, PV ----
    f32x4 opv[4] = {};
    float* arow = attn + ((long long)h * NSEQ + qr) * NSEQ;
    for (int ch = 0; ch < 32; ch++) {
        const int kc = ch * 64;
#pragma unroll
        for (int t = 0; t < 4; t++) {
            const _Float16* kp = Kbase + (long long)(kc + t * 16 + c) * 512;
            f16x8 kb0 = *(const f16x8*)(kp + g * 8);
            f16x8 kb1 = *(const f16x8*)(kp + 32 + g * 8);
            f32x4 acc = {0.f, 0.f, 0.f, 0.f};
            acc = MFMA16(kb0, qa, acc);
            acc = MFMA16(kb1, qb_, acc);
            float e0 = __expf(fminf(acc[0] * 0.125f, 11.f));
            float e1 = __expf(fminf(acc[1] * 0.125f, 11.f));
            float e2 = __expf(fminf(acc[2] * 0.125f, 11.f));
            float e3 = __expf(fminf(acc[3] * 0.125f, 11.f));
            // streamed attn store: row qr, cols kc + t*16 + 4g .. +3
            f32x4 av;
            av[0] = e0 * inv; av[1] = e1 * inv; av[2] = e2 * inv; av[3] = e3 * inv;
            *(f32x4*)(arow + kc + t * 16 + 4 * g) = av;
            // bounce write (fp16 e) for PV A-frag
            f16x2 p01; p01[0] = (_Float16)e0; p01[1] = (_Float16)e1;
            f16x2 p23; p23[0] = (_Float16)e2; p23[1] = (_Float16)e3;
            int b0 = c * 128 + ((t * 32 + g * 8) ^ swz);
            *(f16x2*)(mypb + b0) = p01;
            *(f16x2*)(mypb + b0 + 4) = p23;
        }
        __asm__ volatile("s_waitcnt lgkmcnt(0)" ::: "memory");
        f16x8 p0 = *(const f16x8*)(mypb + c * 128 + ((g * 16) ^ swz));
        f16x8 p1 = *(const f16x8*)(mypb + c * 128 + ((64 + g * 16) ^ swz));
        __asm__ volatile("s_waitcnt lgkmcnt(0)" ::: "memory");
#pragma unroll
        for (int dt = 0; dt < 4; dt++) {
            const _Float16* vp = Vbase + (long long)(dt * 16 + c) * NSEQ + kc;
            f16x8 vb0 = *(const f16x8*)(vp + g * 8);
            f16x8 vb1 = *(const f16x8*)(vp + 32 + g * 8);
            opv[dt] = MFMA16(p0, vb0, opv[dt]);
            opv[dt] = MFMA16(p1, vb1, opv[dt]);
        }
    }

    // ---- epilogue: O rows 4g+j, d = dt*16+c; fetch per-row inv via shfl ----
    float invr[4];
#pragma unroll
    for (int j = 0; j < 4; j++) invr[j] = __shfl(inv, 4 * g + j, 64);
#pragma unroll
    for (int dt = 0; dt < 4; dt++)
#pragma unroll
        for (int j = 0; j < 4; j++)
            AVh[(long long)(qb + w * 16 + 4 * g + j) * DMODEL + h * 64 + dt * 16 + c] =
                (_Float16)(opv[dt][j] * invr[j]);
}

extern "C" void kernel_launch(void* const* d_in, const int* in_sizes, int n_in,
                              void* d_out, int out_size, void* d_ws, size_t ws_size,
                              hipStream_t stream) {
    const float* x  = (const float*)d_in[0];
    const float* Wq = (const float*)d_in[1];
    const float* Wk = (const float*)d_in[2];
    const float* Wv = (const float*)d_in[3];
    const float* Wo = (const float*)d_in[4];
    float* out = (float*)d_out;
    float* attn = out + (size_t)NSEQ * DMODEL;

    char* w = (char*)d_ws;
    auto alloc = [&](size_t bytes) { char* p = w; w += (bytes + 255) & ~(size_t)255; return p; };
    const size_t MD = (size_t)NSEQ * DMODEL;        // 4M elems
    const size_t MKV = (size_t)NSEQ * NKV * DK;     // 1M elems
    _Float16* xh   = (_Float16*)alloc(MD * 2);
    _Float16* WqT  = (_Float16*)alloc(MD * 2);
    _Float16* WkT  = (_Float16*)alloc(MKV * 2);
    _Float16* WvT  = (_Float16*)alloc(MKV * 2);
    _Float16* WoT  = (_Float16*)alloc(MD * 2);
    float2*   cs   = (float2*)alloc((size_t)NSEQ * 32 * sizeof(float2));
    _Float16* Qraw = (_Float16*)alloc(MD * 2);
    _Float16* Kraw = (_Float16*)alloc(MKV * 2);
    _Float16* Kh   = (_Float16*)alloc(MKV * 2);
    _Float16* Vh   = (_Float16*)alloc(MKV * 2);
    _Float16* Vt   = (_Float16*)alloc(MKV * 2);
    _Float16* AVh  = xh;   // reuse (xh dead after projections)

    cvt_f32_f16<<<2048, 256, 0, stream>>>(x, xh, (int)(MD / 4));
    transpose_cvt<<<dim3(DMODEL / 32, DMODEL / 32), dim3(32, 8), 0, stream>>>(Wq, WqT, DMODEL, DMODEL);
    transpose_cvt<<<dim3(512 / 32, DMODEL / 32), dim3(32, 8), 0, stream>>>(Wk, WkT, DMODEL, 512);
    transpose_cvt<<<dim3(512 / 32, DMODEL / 32), dim3(32, 8), 0, stream>>>(Wv, WvT, DMODEL, 512);
    transpose_cvt<<<dim3(DMODEL / 32, DMODEL / 32), dim3(32, 8), 0, stream>>>(Wo, WoT, DMODEL, DMODEL);
    rope_table<<<256, 256, 0, stream>>>(cs);

    gemm_bt<128, 128, 4, 4, _Float16><<<dim3(16, 16), 256, 0, stream>>>(xh, WqT, Qraw, DMODEL, DMODEL, DMODEL, DMODEL);
    gemm_bt<128, 128, 4, 4, _Float16><<<dim3(4, 16), 256, 0, stream>>>(xh, WkT, Kraw, DMODEL, DMODEL, DMODEL, 512);
    gemm_bt<128, 128, 4, 4, _Float16><<<dim3(4, 16), 256, 0, stream>>>(xh, WvT, Vh, DMODEL, DMODEL, DMODEL, 512);

    rope_apply16<<<2048, 256, 0, stream>>>(Kraw, cs, Kh);
    transpose16<<<dim3(512 / 32, NSEQ / 32), dim3(32, 8), 0, stream>>>(Vh, Vt, NSEQ, 512);

    fused_attn<<<dim3(NSEQ / 64, NHEADS), 256, 0, stream>>>(Qraw, cs, Kh, Vt, attn, AVh);

    gemm_bt<128, 128, 4, 4, float><<<dim3(16, 16), 256, 0, stream>>>(AVh, WoT, out, DMODEL, DMODEL, DMODEL, DMODEL);
}

// Round 7
// 643.573 us; speedup vs baseline: 1.1512x; 1.1512x over previous
//
#include <hip/hip_runtime.h>

typedef _Float16 f16x8 __attribute__((ext_vector_type(8)));
typedef _Float16 f16x4 __attribute__((ext_vector_type(4)));
typedef _Float16 f16x2 __attribute__((ext_vector_type(2)));
typedef float f32x4 __attribute__((ext_vector_type(4)));

#define NSEQ 2048
#define DMODEL 2048
#define NHEADS 32
#define NKV 8
#define DK 64
#define MFMA16(a, b, c) __builtin_amdgcn_mfma_f32_16x16x32_f16(a, b, c, 0, 0, 0)

// ---------------- elementwise f32 -> f16 ----------------
__global__ void cvt_f32_f16(const float* __restrict__ in, _Float16* __restrict__ out, int n4) {
    int i = blockIdx.x * blockDim.x + threadIdx.x;
    int stride = gridDim.x * blockDim.x;
    for (; i < n4; i += stride) {
        float4 v = ((const float4*)in)[i];
        f16x4 h;
        h[0] = (_Float16)v.x; h[1] = (_Float16)v.y;
        h[2] = (_Float16)v.z; h[3] = (_Float16)v.w;
        ((f16x4*)out)[i] = h;
    }
}

// ---------------- transpose + convert: in f32 [R][C] -> out f16 [C][R] ----------------
__global__ __launch_bounds__(256) void transpose_cvt(const float* __restrict__ in,
                                                     _Float16* __restrict__ out,
                                                     int R, int C) {
    __shared__ float tile[32][33];
    int c0 = blockIdx.x * 32, r0 = blockIdx.y * 32;
    int tx = threadIdx.x, ty = threadIdx.y; // (32,8)
#pragma unroll
    for (int i = 0; i < 4; i++) {
        int r = r0 + ty + i * 8;
        tile[ty + i * 8][tx] = in[(long long)r * C + c0 + tx];
    }
    __syncthreads();
#pragma unroll
    for (int i = 0; i < 4; i++) {
        int c = c0 + ty + i * 8;
        out[(long long)c * R + r0 + tx] = (_Float16)tile[tx][ty + i * 8];
    }
}

// ---------------- transpose f16 [R][C] -> f16 [C][R] ----------------
__global__ __launch_bounds__(256) void transpose16(const _Float16* __restrict__ in,
                                                   _Float16* __restrict__ out,
                                                   int R, int C) {
    __shared__ _Float16 tile[32][34];
    int c0 = blockIdx.x * 32, r0 = blockIdx.y * 32;
    int tx = threadIdx.x, ty = threadIdx.y; // (32,8)
#pragma unroll
    for (int i = 0; i < 4; i++) {
        int r = r0 + ty + i * 8;
        tile[ty + i * 8][tx] = in[(long long)r * C + c0 + tx];
    }
    __syncthreads();
#pragma unroll
    for (int i = 0; i < 4; i++) {
        int c = c0 + ty + i * 8;
        out[(long long)c * R + r0 + tx] = tile[tx][ty + i * 8];
    }
}

// ---------------- RoPE cos/sin table ----------------
__global__ void rope_table(float2* __restrict__ cs) {
    int idx = blockIdx.x * blockDim.x + threadIdx.x; // 65536 total
    int n = idx >> 5, j = idx & 31;
    float e = (2.0f * j) / 64.0f;
    float invf = 1.0f / powf(10000.0f, e);
    float ang = (float)n * invf;
    float2 v; v.x = cosf(ang); v.y = sinf(ang);
    cs[idx] = v;
}

// ---------------- RoPE apply f16->f16 for K (ncols=512) ----------------
__global__ void rope_apply16(const _Float16* __restrict__ in, const float2* __restrict__ cs,
                             _Float16* __restrict__ out) {
    int idx = blockIdx.x * blockDim.x + threadIdx.x; // 2048*256
    int n = idx >> 8, rem = idx & 255;
    int hk = rem >> 5, j = rem & 31;
    float2 c = cs[n * 32 + j];
    long long base = (long long)n * 512 + hk * 64;
    float x1 = (float)in[base + j], x2 = (float)in[base + j + 32];
    out[base + j]      = (_Float16)(x1 * c.x - x2 * c.y);
    out[base + j + 32] = (_Float16)(x2 * c.x + x1 * c.y);
}

// ---------------- GEMM: C[M,N] = A[M,K] @ Bt[N,K]^T  (fp16 MFMA, f32 accum) ----------------
template <int BM, int BN, int MF, int NF, typename OutT>
__global__ __launch_bounds__(256) void gemm_bt(const _Float16* __restrict__ Ap,
                                               const _Float16* __restrict__ Bt,
                                               OutT* __restrict__ C,
                                               int K, int lda, int ldb, int ldc) {
    constexpr int LDP = 56;
    __shared__ __align__(16) _Float16 As[BM][LDP];
    __shared__ __align__(16) _Float16 Bs[BN][LDP];

    const int tid = threadIdx.x;
    const int lane = tid & 63, wid = tid >> 6;
    constexpr int WC = BN / (NF * 16);
    const int wr = wid / WC, wc = wid % WC;
    const int wm = wr * MF * 16, wn = wc * NF * 16;
    const int am = lane & 15;
    const int k0 = (lane >> 4) * 8;

    f32x4 acc[MF][NF] = {};

    const long long a_row0 = (long long)blockIdx.y * BM * lda;
    const long long b_row0 = (long long)blockIdx.x * BN * ldb;

    for (int kt = 0; kt < K; kt += 32) {
        const _Float16* A = Ap + a_row0 + kt;
        for (int c = tid; c < BM * 4; c += 256) {
            int r = c >> 2, s = c & 3;
            *(f16x8*)&As[r][s * 8] = *(const f16x8*)(A + (long long)r * lda + s * 8);
        }
        const _Float16* B = Bt + b_row0 + kt;
        for (int c = tid; c < BN * 4; c += 256) {
            int r = c >> 2, s = c & 3;
            *(f16x8*)&Bs[r][s * 8] = *(const f16x8*)(B + (long long)r * ldb + s * 8);
        }
        __syncthreads();

        f16x8 af[MF], bf[NF];
#pragma unroll
        for (int m = 0; m < MF; m++) af[m] = *(const f16x8*)&As[wm + m * 16 + am][k0];
#pragma unroll
        for (int n = 0; n < NF; n++) bf[n] = *(const f16x8*)&Bs[wn + n * 16 + am][k0];
#pragma unroll
        for (int m = 0; m < MF; m++)
#pragma unroll
            for (int n = 0; n < NF; n++)
                acc[m][n] = MFMA16(af[m], bf[n], acc[m][n]);
        __syncthreads();
    }

    const int rb = blockIdx.y * BM + wm + (lane >> 4) * 4;
    const int cb = blockIdx.x * BN + wn + am;
#pragma unroll
    for (int m = 0; m < MF; m++)
#pragma unroll
        for (int n = 0; n < NF; n++)
#pragma unroll
            for (int j = 0; j < 4; j++)
                C[(long long)(rb + m * 16 + j) * ldc + cb + n * 16] = (OutT)acc[m][n][j];
}

// ---------------- fused attention v5: single QK pass -> E in LDS, row-contiguous stores ----
// 512 thr / 8 waves; block = 16 Q-rows. Wave w owns kcols [w*256, +256) for QK.
// Swapped QK^T (mfma(K,Q)): lane (g,c) holds S[qrow=c][kcol = base+4g+j]; e=exp(min(s,11)) fp16
// into E[16][2048] (row pitch 4096B, byte ^= (row&7)<<4 swizzle; v2-validated layout).
// Row sums in registers (2 shfl_xor) + one cross-wave LDS merge.
// Stores: wave w writes rows {w, w+8} FULLY CONTIGUOUSLY: 8 x 1KB f32x4 wave-instrs per row.
// PV: wave w -> d-block (w&3), k-half (w>>2); A-frags from E, B-frags from Vt; pair-reduce in LDS.
__global__ __launch_bounds__(512) void fused_attn(
    const _Float16* __restrict__ Qraw, // [2048][2048] pre-rope fp16
    const float2*  __restrict__ cs,    // [2048][32]
    const _Float16* __restrict__ Kh,   // [2048][512] roped
    const _Float16* __restrict__ Vt,   // [512][2048]
    float* __restrict__ attn,          // [32][2048][2048]
    _Float16* __restrict__ AVh)        // [2048][2048]
{
    __shared__ __align__(16) _Float16 E[16 * 2048]; // 64 KB
    __shared__ float Ored[2][16][64];               // 8 KB
    __shared__ float lsum[8][16], s_inv[16];

    const int h = blockIdx.y, q0 = blockIdx.x * 16;
    const int kvh = h >> 2;
    const int tid = threadIdx.x, lane = tid & 63, w = tid >> 6;
    const int g = lane >> 4, c = lane & 15;

    // ---- Q fragment (B-operand, Q-row = c) + in-register RoPE ----
    const _Float16* qp = Qraw + (long long)(q0 + c) * DMODEL + h * 64;
    f16x8 q0v = *(const f16x8*)(qp + g * 8);
    f16x8 q1v = *(const f16x8*)(qp + 32 + g * 8);
    const float2* csp = cs + (q0 + c) * 32 + g * 8;
    f16x8 qa, qb_;
#pragma unroll
    for (int e = 0; e < 8; e++) {
        float2 cv = csp[e];
        float x1 = (float)q0v[e], x2 = (float)q1v[e];
        qa[e]  = (_Float16)(x1 * cv.x - x2 * cv.y);
        qb_[e] = (_Float16)(x2 * cv.x + x1 * cv.y);
    }

    const _Float16* Kbase = Kh + kvh * 64;
    const _Float16* Vbase = Vt + (long long)(kvh * 64) * NSEQ;
    const int swz = (c & 7) << 4;
    const int kw = w * 256;

    // ---- QK over this wave's strip: e -> E, row sums in regs ----
    float l = 0.f;
#pragma unroll 4
    for (int t2 = 0; t2 < 16; t2++) {
        const int kcolb = kw + t2 * 16;
        const _Float16* kp = Kbase + (long long)(kcolb + c) * 512;
        f16x8 kb0 = *(const f16x8*)(kp + g * 8);
        f16x8 kb1 = *(const f16x8*)(kp + 32 + g * 8);
        f32x4 acc = {0.f, 0.f, 0.f, 0.f};
        acc = MFMA16(kb0, qa, acc);
        acc = MFMA16(kb1, qb_, acc);
        float e0 = __expf(fminf(acc[0] * 0.125f, 11.f));
        float e1 = __expf(fminf(acc[1] * 0.125f, 11.f));
        float e2 = __expf(fminf(acc[2] * 0.125f, 11.f));
        float e3 = __expf(fminf(acc[3] * 0.125f, 11.f));
        l += (e0 + e1) + (e2 + e3);
        f16x2 p01; p01[0] = (_Float16)e0; p01[1] = (_Float16)e1;
        f16x2 p23; p23[0] = (_Float16)e2; p23[1] = (_Float16)e3;
        // row c, cols kcolb + 4g + {0..3}
        int b0 = c * 4096 + (((kcolb + 4 * g) * 2) ^ swz);
        *(f16x2*)((char*)E + b0) = p01;
        *(f16x2*)((char*)E + b0 + 4) = p23;
    }
    l += __shfl_xor(l, 16, 64);
    l += __shfl_xor(l, 32, 64);
    if (lane < 16) lsum[w][lane] = l;
    __syncthreads();
    if (tid < 16) {
        float S = 0.f;
#pragma unroll
        for (int w2 = 0; w2 < 8; w2++) S += lsum[w2][tid];
        s_inv[tid] = 1.0f / S;
    }
    __syncthreads();

    // ---- attn stores: wave w writes rows {w, w+8}, 1KB-contiguous wave-instrs ----
#pragma unroll
    for (int rr2 = 0; rr2 < 2; rr2++) {
        const int r = w + rr2 * 8;
        const float inv = s_inv[r];
        const int swr = (r & 7) << 4;
        float* arow = attn + ((long long)h * NSEQ + q0 + r) * NSEQ;
        const char* erow = (const char*)E + r * 4096;
#pragma unroll
        for (int i = 0; i < 8; i++) {
            f16x4 ev = *(const f16x4*)(erow + ((i * 512 + lane * 8) ^ swr));
            f32x4 o;
            o[0] = (float)ev[0] * inv; o[1] = (float)ev[1] * inv;
            o[2] = (float)ev[2] * inv; o[3] = (float)ev[3] * inv;
            *(f32x4*)(arow + i * 256 + lane * 4) = o;
        }
    }

    // ---- PV: wave w -> d-block dt = w&3, k-half kh = w>>2 ----
    const int dt = w & 3, kh = w >> 2;
    f32x4 opv = {0.f, 0.f, 0.f, 0.f};
    const _Float16* vrow = Vbase + (long long)(dt * 16 + c) * NSEQ + kh * 1024;
    const char* erowc = (const char*)E + c * 4096;
#pragma unroll 4
    for (int kk = 0; kk < 1024; kk += 32) {
        f16x8 pa = *(const f16x8*)(erowc + (((kh * 1024 + kk + g * 8) * 2) ^ swz));
        f16x8 vb = *(const f16x8*)(vrow + kk + g * 8);
        opv = MFMA16(pa, vb, opv);
    }
#pragma unroll
    for (int j = 0; j < 4; j++) Ored[kh][4 * g + j][dt * 16 + c] = opv[j];
    __syncthreads();

    // ---- merge halves -> AVh ----
    const int r = tid >> 5, d2 = (tid & 31) * 2;
    float a0 = Ored[0][r][d2] + Ored[1][r][d2];
    float a1 = Ored[0][r][d2 + 1] + Ored[1][r][d2 + 1];
    const float iv = s_inv[r];
    f16x2 o; o[0] = (_Float16)(a0 * iv); o[1] = (_Float16)(a1 * iv);
    *(f16x2*)(AVh + (long long)(q0 + r) * DMODEL + h * 64 + d2) = o;
}

extern "C" void kernel_launch(void* const* d_in, const int* in_sizes, int n_in,
                              void* d_out, int out_size, void* d_ws, size_t ws_size,
                              hipStream_t stream) {
    const float* x  = (const float*)d_in[0];
    const float* Wq = (const float*)d_in[1];
    const float* Wk = (const float*)d_in[2];
    const float* Wv = (const float*)d_in[3];
    const float* Wo = (const float*)d_in[4];
    float* out = (float*)d_out;
    float* attn = out + (size_t)NSEQ * DMODEL;

    char* w = (char*)d_ws;
    auto alloc = [&](size_t bytes) { char* p = w; w += (bytes + 255) & ~(size_t)255; return p; };
    const size_t MD = (size_t)NSEQ * DMODEL;        // 4M elems
    const size_t MKV = (size_t)NSEQ * NKV * DK;     // 1M elems
    _Float16* xh   = (_Float16*)alloc(MD * 2);
    _Float16* WqT  = (_Float16*)alloc(MD * 2);
    _Float16* WkT  = (_Float16*)alloc(MKV * 2);
    _Float16* WvT  = (_Float16*)alloc(MKV * 2);
    _Float16* WoT  = (_Float16*)alloc(MD * 2);
    float2*   cs   = (float2*)alloc((size_t)NSEQ * 32 * sizeof(float2));
    _Float16* Qraw = (_Float16*)alloc(MD * 2);
    _Float16* Kraw = (_Float16*)alloc(MKV * 2);
    _Float16* Kh   = (_Float16*)alloc(MKV * 2);
    _Float16* Vh   = (_Float16*)alloc(MKV * 2);
    _Float16* Vt   = (_Float16*)alloc(MKV * 2);
    _Float16* AVh  = xh;   // reuse (xh dead after projections)

    cvt_f32_f16<<<2048, 256, 0, stream>>>(x, xh, (int)(MD / 4));
    transpose_cvt<<<dim3(DMODEL / 32, DMODEL / 32), dim3(32, 8), 0, stream>>>(Wq, WqT, DMODEL, DMODEL);
    transpose_cvt<<<dim3(512 / 32, DMODEL / 32), dim3(32, 8), 0, stream>>>(Wk, WkT, DMODEL, 512);
    transpose_cvt<<<dim3(512 / 32, DMODEL / 32), dim3(32, 8), 0, stream>>>(Wv, WvT, DMODEL, 512);
    transpose_cvt<<<dim3(DMODEL / 32, DMODEL / 32), dim3(32, 8), 0, stream>>>(Wo, WoT, DMODEL, DMODEL);
    rope_table<<<256, 256, 0, stream>>>(cs);

    gemm_bt<128, 128, 4, 4, _Float16><<<dim3(16, 16), 256, 0, stream>>>(xh, WqT, Qraw, DMODEL, DMODEL, DMODEL, DMODEL);
    gemm_bt<128, 128, 4, 4, _Float16><<<dim3(4, 16), 256, 0, stream>>>(xh, WkT, Kraw, DMODEL, DMODEL, DMODEL, 512);
    gemm_bt<128, 128, 4, 4, _Float16><<<dim3(4, 16), 256, 0, stream>>>(xh, WvT, Vh, DMODEL, DMODEL, DMODEL, 512);

    rope_apply16<<<2048, 256, 0, stream>>>(Kraw, cs, Kh);
    transpose16<<<dim3(512 / 32, NSEQ / 32), dim3(32, 8), 0, stream>>>(Vh, Vt, NSEQ, 512);

    fused_attn<<<dim3(NSEQ / 16, NHEADS), 512, 0, stream>>>(Qraw, cs, Kh, Vt, attn, AVh);

    gemm_bt<128, 128, 4, 4, float><<<dim3(16, 16), 256, 0, stream>>>(AVh, WoT, out, DMODEL, DMODEL, DMODEL, DMODEL);
}

// Round 8
// 527.864 us; speedup vs baseline: 1.4035x; 1.2192x over previous
//
#include <hip/hip_runtime.h>

typedef _Float16 f16x8 __attribute__((ext_vector_type(8)));
typedef _Float16 f16x4 __attribute__((ext_vector_type(4)));
typedef _Float16 f16x2 __attribute__((ext_vector_type(2)));
typedef float f32x4 __attribute__((ext_vector_type(4)));

#define NSEQ 2048
#define DMODEL 2048
#define NHEADS 32
#define NKV 8
#define DK 64
#define MFMA16(a, b, c) __builtin_amdgcn_mfma_f32_16x16x32_f16(a, b, c, 0, 0, 0)

// async global->LDS, 16B per lane; LDS dest is wave-uniform base + lane*16
__device__ __forceinline__ void gload16(const void* g, void* l) {
    __builtin_amdgcn_global_load_lds(
        (const __attribute__((address_space(1))) void*)g,
        (__attribute__((address_space(3))) void*)l, 16, 0, 0);
}

// ---------------- elementwise f32 -> f16 ----------------
__global__ void cvt_f32_f16(const float* __restrict__ in, _Float16* __restrict__ out, int n4) {
    int i = blockIdx.x * blockDim.x + threadIdx.x;
    int stride = gridDim.x * blockDim.x;
    for (; i < n4; i += stride) {
        float4 v = ((const float4*)in)[i];
        f16x4 h;
        h[0] = (_Float16)v.x; h[1] = (_Float16)v.y;
        h[2] = (_Float16)v.z; h[3] = (_Float16)v.w;
        ((f16x4*)out)[i] = h;
    }
}

// ---------------- transpose + convert: in f32 [R][C] -> out f16 [C][R] ----------------
__global__ __launch_bounds__(256) void transpose_cvt(const float* __restrict__ in,
                                                     _Float16* __restrict__ out,
                                                     int R, int C) {
    __shared__ float tile[32][33];
    int c0 = blockIdx.x * 32, r0 = blockIdx.y * 32;
    int tx = threadIdx.x, ty = threadIdx.y; // (32,8)
#pragma unroll
    for (int i = 0; i < 4; i++) {
        int r = r0 + ty + i * 8;
        tile[ty + i * 8][tx] = in[(long long)r * C + c0 + tx];
    }
    __syncthreads();
#pragma unroll
    for (int i = 0; i < 4; i++) {
        int c = c0 + ty + i * 8;
        out[(long long)c * R + r0 + tx] = (_Float16)tile[tx][ty + i * 8];
    }
}

// ---------------- transpose f16 [R][C] -> f16 [C][R] ----------------
__global__ __launch_bounds__(256) void transpose16(const _Float16* __restrict__ in,
                                                   _Float16* __restrict__ out,
                                                   int R, int C) {
    __shared__ _Float16 tile[32][34];
    int c0 = blockIdx.x * 32, r0 = blockIdx.y * 32;
    int tx = threadIdx.x, ty = threadIdx.y; // (32,8)
#pragma unroll
    for (int i = 0; i < 4; i++) {
        int r = r0 + ty + i * 8;
        tile[ty + i * 8][tx] = in[(long long)r * C + c0 + tx];
    }
    __syncthreads();
#pragma unroll
    for (int i = 0; i < 4; i++) {
        int c = c0 + ty + i * 8;
        out[(long long)c * R + r0 + tx] = tile[tx][ty + i * 8];
    }
}

// ---------------- RoPE cos/sin table ----------------
__global__ void rope_table(float2* __restrict__ cs) {
    int idx = blockIdx.x * blockDim.x + threadIdx.x; // 65536 total
    int n = idx >> 5, j = idx & 31;
    float e = (2.0f * j) / 64.0f;
    float invf = 1.0f / powf(10000.0f, e);
    float ang = (float)n * invf;
    float2 v; v.x = cosf(ang); v.y = sinf(ang);
    cs[idx] = v;
}

// ---------------- RoPE apply f16->f16 for K (ncols=512) ----------------
__global__ void rope_apply16(const _Float16* __restrict__ in, const float2* __restrict__ cs,
                             _Float16* __restrict__ out) {
    int idx = blockIdx.x * blockDim.x + threadIdx.x; // 2048*256
    int n = idx >> 8, rem = idx & 255;
    int hk = rem >> 5, j = rem & 31;
    float2 c = cs[n * 32 + j];
    long long base = (long long)n * 512 + hk * 64;
    float x1 = (float)in[base + j], x2 = (float)in[base + j + 32];
    out[base + j]      = (_Float16)(x1 * c.x - x2 * c.y);
    out[base + j + 32] = (_Float16)(x2 * c.x + x1 * c.y);
}

// ---------------- GEMM (m97 structure): C[M,N] = A[M,K] @ Bt[N,K]^T ----------------
// global_load_lds width-16 staging into LINEAR (unpadded) LDS tiles [rows][32 halfs = 64B].
// Per K-step: wave w stages rows [w*BM/4, +BM/4) of A (and BN/4 of B), 1KB per instr:
//   lane i -> row base + i/4, byte (i&3)*16  == linear byte i*16 within the chunk.
// Frags: af[m] = As row (wm+m*16+am), halfs [g*8, +8)  (A/B same k-order => dot invariant).
template <int BM, int BN, int MF, int NF, typename OutT>
__global__ __launch_bounds__(256) void gemm_lds(const _Float16* __restrict__ Ap,
                                                const _Float16* __restrict__ Bt,
                                                OutT* __restrict__ C,
                                                int K, int lda, int ldb, int ldc) {
    __shared__ __align__(16) _Float16 As[BM * 32];
    __shared__ __align__(16) _Float16 Bs[BN * 32];

    const int tid = threadIdx.x;
    const int lane = tid & 63, w = tid >> 6;
    constexpr int WC = BN / (NF * 16);
    const int wr = w / WC, wc = w % WC;
    const int wm = wr * MF * 16, wn = wc * NF * 16;
    const int am = lane & 15;
    const int g = lane >> 4;

    f32x4 acc[MF][NF] = {};

    const long long a_row0 = (long long)blockIdx.y * BM * lda;
    const long long b_row0 = (long long)blockIdx.x * BN * ldb;

    const int srow = lane >> 2;        // staging: row within 16-row group
    const int scol = (lane & 3) * 8;   // staging: halfs offset within row

    for (int kt = 0; kt < K; kt += 32) {
#pragma unroll
        for (int q = 0; q < BM / 64; q++) {
            const int row = w * (BM / 4) + q * 16 + srow;
            gload16(Ap + a_row0 + (long long)row * lda + kt + scol,
                    &As[w * (BM * 8) + q * 512]);
        }
#pragma unroll
        for (int q = 0; q < BN / 64; q++) {
            const int row = w * (BN / 4) + q * 16 + srow;
            gload16(Bt + b_row0 + (long long)row * ldb + kt + scol,
                    &Bs[w * (BN * 8) + q * 512]);
        }
        __syncthreads();

        f16x8 af[MF], bf[NF];
#pragma unroll
        for (int m = 0; m < MF; m++) af[m] = *(const f16x8*)&As[(wm + m * 16 + am) * 32 + g * 8];
#pragma unroll
        for (int n = 0; n < NF; n++) bf[n] = *(const f16x8*)&Bs[(wn + n * 16 + am) * 32 + g * 8];
#pragma unroll
        for (int m = 0; m < MF; m++)
#pragma unroll
            for (int n = 0; n < NF; n++)
                acc[m][n] = MFMA16(af[m], bf[n], acc[m][n]);
        __syncthreads();
    }

    const int rb = blockIdx.y * BM + wm + (lane >> 4) * 4;
    const int cb = blockIdx.x * BN + wn + am;
#pragma unroll
    for (int m = 0; m < MF; m++)
#pragma unroll
        for (int n = 0; n < NF; n++)
#pragma unroll
            for (int j = 0; j < 4; j++)
                C[(long long)(rb + m * 16 + j) * ldc + cb + n * 16] = (OutT)acc[m][n][j];
}

// ---------------- fused attention v5: single QK pass -> E in LDS, row-contiguous stores ----
// (unchanged from round 7 — isolating the GEMM change this round)
__global__ __launch_bounds__(512) void fused_attn(
    const _Float16* __restrict__ Qraw, // [2048][2048] pre-rope fp16
    const float2*  __restrict__ cs,    // [2048][32]
    const _Float16* __restrict__ Kh,   // [2048][512] roped
    const _Float16* __restrict__ Vt,   // [512][2048]
    float* __restrict__ attn,          // [32][2048][2048]
    _Float16* __restrict__ AVh)        // [2048][2048]
{
    __shared__ __align__(16) _Float16 E[16 * 2048]; // 64 KB
    __shared__ float Ored[2][16][64];               // 8 KB
    __shared__ float lsum[8][16], s_inv[16];

    const int h = blockIdx.y, q0 = blockIdx.x * 16;
    const int kvh = h >> 2;
    const int tid = threadIdx.x, lane = tid & 63, w = tid >> 6;
    const int g = lane >> 4, c = lane & 15;

    // ---- Q fragment (B-operand, Q-row = c) + in-register RoPE ----
    const _Float16* qp = Qraw + (long long)(q0 + c) * DMODEL + h * 64;
    f16x8 q0v = *(const f16x8*)(qp + g * 8);
    f16x8 q1v = *(const f16x8*)(qp + 32 + g * 8);
    const float2* csp = cs + (q0 + c) * 32 + g * 8;
    f16x8 qa, qb_;
#pragma unroll
    for (int e = 0; e < 8; e++) {
        float2 cv = csp[e];
        float x1 = (float)q0v[e], x2 = (float)q1v[e];
        qa[e]  = (_Float16)(x1 * cv.x - x2 * cv.y);
        qb_[e] = (_Float16)(x2 * cv.x + x1 * cv.y);
    }

    const _Float16* Kbase = Kh + kvh * 64;
    const _Float16* Vbase = Vt + (long long)(kvh * 64) * NSEQ;
    const int swz = (c & 7) << 4;
    const int kw = w * 256;

    // ---- QK over this wave's strip: e -> E, row sums in regs ----
    float l = 0.f;
#pragma unroll 4
    for (int t2 = 0; t2 < 16; t2++) {
        const int kcolb = kw + t2 * 16;
        const _Float16* kp = Kbase + (long long)(kcolb + c) * 512;
        f16x8 kb0 = *(const f16x8*)(kp + g * 8);
        f16x8 kb1 = *(const f16x8*)(kp + 32 + g * 8);
        f32x4 acc = {0.f, 0.f, 0.f, 0.f};
        acc = MFMA16(kb0, qa, acc);
        acc = MFMA16(kb1, qb_, acc);
        float e0 = __expf(fminf(acc[0] * 0.125f, 11.f));
        float e1 = __expf(fminf(acc[1] * 0.125f, 11.f));
        float e2 = __expf(fminf(acc[2] * 0.125f, 11.f));
        float e3 = __expf(fminf(acc[3] * 0.125f, 11.f));
        l += (e0 + e1) + (e2 + e3);
        f16x2 p01; p01[0] = (_Float16)e0; p01[1] = (_Float16)e1;
        f16x2 p23; p23[0] = (_Float16)e2; p23[1] = (_Float16)e3;
        int b0 = c * 4096 + (((kcolb + 4 * g) * 2) ^ swz);
        *(f16x2*)((char*)E + b0) = p01;
        *(f16x2*)((char*)E + b0 + 4) = p23;
    }
    l += __shfl_xor(l, 16, 64);
    l += __shfl_xor(l, 32, 64);
    if (lane < 16) lsum[w][lane] = l;
    __syncthreads();
    if (tid < 16) {
        float S = 0.f;
#pragma unroll
        for (int w2 = 0; w2 < 8; w2++) S += lsum[w2][tid];
        s_inv[tid] = 1.0f / S;
    }
    __syncthreads();

    // ---- attn stores: wave w writes rows {w, w+8}, 1KB-contiguous wave-instrs ----
#pragma unroll
    for (int rr2 = 0; rr2 < 2; rr2++) {
        const int r = w + rr2 * 8;
        const float inv = s_inv[r];
        const int swr = (r & 7) << 4;
        float* arow = attn + ((long long)h * NSEQ + q0 + r) * NSEQ;
        const char* erow = (const char*)E + r * 4096;
#pragma unroll
        for (int i = 0; i < 8; i++) {
            f16x4 ev = *(const f16x4*)(erow + ((i * 512 + lane * 8) ^ swr));
            f32x4 o;
            o[0] = (float)ev[0] * inv; o[1] = (float)ev[1] * inv;
            o[2] = (float)ev[2] * inv; o[3] = (float)ev[3] * inv;
            *(f32x4*)(arow + i * 256 + lane * 4) = o;
        }
    }

    // ---- PV: wave w -> d-block dt = w&3, k-half kh = w>>2 ----
    const int dt = w & 3, kh = w >> 2;
    f32x4 opv = {0.f, 0.f, 0.f, 0.f};
    const _Float16* vrow = Vbase + (long long)(dt * 16 + c) * NSEQ + kh * 1024;
    const char* erowc = (const char*)E + c * 4096;
#pragma unroll 4
    for (int kk = 0; kk < 1024; kk += 32) {
        f16x8 pa = *(const f16x8*)(erowc + (((kh * 1024 + kk + g * 8) * 2) ^ swz));
        f16x8 vb = *(const f16x8*)(vrow + kk + g * 8);
        opv = MFMA16(pa, vb, opv);
    }
#pragma unroll
    for (int j = 0; j < 4; j++) Ored[kh][4 * g + j][dt * 16 + c] = opv[j];
    __syncthreads();

    // ---- merge halves -> AVh ----
    const int r = tid >> 5, d2 = (tid & 31) * 2;
    float a0 = Ored[0][r][d2] + Ored[1][r][d2];
    float a1 = Ored[0][r][d2 + 1] + Ored[1][r][d2 + 1];
    const float iv = s_inv[r];
    f16x2 o; o[0] = (_Float16)(a0 * iv); o[1] = (_Float16)(a1 * iv);
    *(f16x2*)(AVh + (long long)(q0 + r) * DMODEL + h * 64 + d2) = o;
}

extern "C" void kernel_launch(void* const* d_in, const int* in_sizes, int n_in,
                              void* d_out, int out_size, void* d_ws, size_t ws_size,
                              hipStream_t stream) {
    const float* x  = (const float*)d_in[0];
    const float* Wq = (const float*)d_in[1];
    const float* Wk = (const float*)d_in[2];
    const float* Wv = (const float*)d_in[3];
    const float* Wo = (const float*)d_in[4];
    float* out = (float*)d_out;
    float* attn = out + (size_t)NSEQ * DMODEL;

    char* w = (char*)d_ws;
    auto alloc = [&](size_t bytes) { char* p = w; w += (bytes + 255) & ~(size_t)255; return p; };
    const size_t MD = (size_t)NSEQ * DMODEL;        // 4M elems
    const size_t MKV = (size_t)NSEQ * NKV * DK;     // 1M elems
    _Float16* xh   = (_Float16*)alloc(MD * 2);
    _Float16* WqT  = (_Float16*)alloc(MD * 2);
    _Float16* WkT  = (_Float16*)alloc(MKV * 2);
    _Float16* WvT  = (_Float16*)alloc(MKV * 2);
    _Float16* WoT  = (_Float16*)alloc(MD * 2);
    float2*   cs   = (float2*)alloc((size_t)NSEQ * 32 * sizeof(float2));
    _Float16* Qraw = (_Float16*)alloc(MD * 2);
    _Float16* Kraw = (_Float16*)alloc(MKV * 2);
    _Float16* Kh   = (_Float16*)alloc(MKV * 2);
    _Float16* Vh   = (_Float16*)alloc(MKV * 2);
    _Float16* Vt   = (_Float16*)alloc(MKV * 2);
    _Float16* AVh  = xh;   // reuse (xh dead after projections)

    cvt_f32_f16<<<2048, 256, 0, stream>>>(x, xh, (int)(MD / 4));
    transpose_cvt<<<dim3(DMODEL / 32, DMODEL / 32), dim3(32, 8), 0, stream>>>(Wq, WqT, DMODEL, DMODEL);
    transpose_cvt<<<dim3(512 / 32, DMODEL / 32), dim3(32, 8), 0, stream>>>(Wk, WkT, DMODEL, 512);
    transpose_cvt<<<dim3(512 / 32, DMODEL / 32), dim3(32, 8), 0, stream>>>(Wv, WvT, DMODEL, 512);
    transpose_cvt<<<dim3(DMODEL / 32, DMODEL / 32), dim3(32, 8), 0, stream>>>(Wo, WoT, DMODEL, DMODEL);
    rope_table<<<256, 256, 0, stream>>>(cs);

    gemm_lds<128, 128, 4, 4, _Float16><<<dim3(16, 16), 256, 0, stream>>>(xh, WqT, Qraw, DMODEL, DMODEL, DMODEL, DMODEL);
    gemm_lds<128, 128, 4, 4, _Float16><<<dim3(4, 16), 256, 0, stream>>>(xh, WkT, Kraw, DMODEL, DMODEL, DMODEL, 512);
    gemm_lds<128, 128, 4, 4, _Float16><<<dim3(4, 16), 256, 0, stream>>>(xh, WvT, Vh, DMODEL, DMODEL, DMODEL, 512);

    rope_apply16<<<2048, 256, 0, stream>>>(Kraw, cs, Kh);
    transpose16<<<dim3(512 / 32, NSEQ / 32), dim3(32, 8), 0, stream>>>(Vh, Vt, NSEQ, 512);

    fused_attn<<<dim3(NSEQ / 16, NHEADS), 512, 0, stream>>>(Qraw, cs, Kh, Vt, attn, AVh);

    gemm_lds<128, 128, 4, 4, float><<<dim3(16, 16), 256, 0, stream>>>(AVh, WoT, out, DMODEL, DMODEL, DMODEL, DMODEL);
}